// Round 1
// baseline (165.157 us; speedup 1.0000x reference)
//
#include <hip/hip_runtime.h>

// h: (2,1,1,16,16) fp32 | gi: (2,M,16) | gj: (2,M,16) | theta: (2,M) | out: (2,16,16)
//
// History: R2 VGPR spill 199us. R3/R4 VGPR-loads 48us (16 waves/CU, shallow
// prefetch, latency-exposed). R5 barrier-coupled LDS dbuf 53us. R7 per-wave
// private LDS staging, DEPTH=3, 512 blocks (2/CU, 8 waves/CU): 51us,
// VALUBusy 22%, Occupancy 15% -> latency-bound, ~2.6 TB/s effective.
// R8 (this): raise per-CU memory parallelism. DEPTH=2 shrinks LDS/block to
// 33792 B -> 4 blocks/CU = 16 waves/CU (2x issue streams), grid 1024 = exact
// residency, no tail. Wait order restructured to wait(6)->compute->stage so
// each wave holds ~12 loads in flight through the whole stall window
// (~130 KB/CU in flight vs 85 KB before). lgkmcnt(0) fence between compute
// and restage: DEPTH=2 overwrites the just-read buffer, and ds_read service
// has no HW ordering vs the VMEM->LDS write-return path.

constexpr int MDIM    = 524288;
constexpr int THREADS = 256;
constexpr int BLOCKS  = 1024;             // 4 blocks/CU (LDS-pinned: 4*33792 = 135168 <= 163840)
constexpr int M_PER_B = MDIM / BLOCKS;    // 512
constexpr int M_PER_W = M_PER_B / 4;      // 128 m per wave
constexpr int CHUNK   = 16;               // m per chunk
constexpr int NCH     = M_PER_W / CHUNK;  // 8 chunks per wave
constexpr int DEPTH   = 2;                // buffers per wave (1 prefetched ahead)

// Per-buffer float offsets: e[256] f[256] a[256] b[256] t0[16] t1[16]
constexpr int E_OFF = 0, F_OFF = 256, A_OFF = 512, B_OFF = 768;
constexpr int T0_OFF = 1024, T1_OFF = 1040;
constexpr int BUF_F  = 1056;
constexpr int WAVE_F = DEPTH * BUF_F;     // 2112 floats per wave
constexpr int SMEM_F = 4 * WAVE_F;        // 8448 floats = 33792 B
static_assert(SMEM_F * sizeof(float) <= 40960, "need <= 40 KiB for 4 blocks/CU");
static_assert(NCH >= 3, "pipeline needs at least 3 chunks");

typedef float f32x2 __attribute__((ext_vector_type(2)));

#define AS1 __attribute__((address_space(1)))
#define AS3 __attribute__((address_space(3)))

__device__ __forceinline__ void cp16(const float* g, float* l) {
    __builtin_amdgcn_global_load_lds((const AS1 void*)g, (AS3 void*)l, 16, 0, 0);
}
__device__ __forceinline__ void cp4(const float* g, float* l) {
    __builtin_amdgcn_global_load_lds((const AS1 void*)g, (AS3 void*)l, 4, 0, 0);
}

// Stage chunk p into `buf`. Exactly 6 VMEM instructions per call for every
// wave (4 cp16 + 2 exec-masked cp4) — the vmcnt arithmetic depends on this.
__device__ __forceinline__ void stage(
    const float* e_g, const float* f_g, const float* a_g, const float* b_g,
    const float* t0_g, const float* t1_g, float* buf, int p, int lane)
{
    const size_t mo = (size_t)p * (CHUNK * 16);   // 256 floats per chunk
    cp16(e_g + mo, buf + E_OFF);
    cp16(f_g + mo, buf + F_OFF);
    cp16(a_g + mo, buf + A_OFF);
    cp16(b_g + mo, buf + B_OFF);
    if (lane < 16) {
        cp4(t0_g + (size_t)p * CHUNK, buf + T0_OFF);
        cp4(t1_g + (size_t)p * CHUNK, buf + T1_OFF);
    }
}

__device__ __forceinline__ void compute_chunk(
    const float* buf, int slot, int i0, int j0,
    f32x2 (&are)[4][2], f32x2 (&aim)[4][2])
{
#pragma unroll
    for (int k = 0; k < 4; ++k) {
        const int ml = slot + 4 * k;             // 16 m per chunk, 4 per k-step
        const float4 e4 = *(const float4*)(buf + E_OFF + ml * 16 + i0);
        const float4 f4 = *(const float4*)(buf + F_OFF + ml * 16 + i0);
        const float4 a4 = *(const float4*)(buf + A_OFF + ml * 16 + j0);
        const float4 b4 = *(const float4*)(buf + B_OFF + ml * 16 + j0);
        const float c = __cosf(buf[T0_OFF + ml]);
        const float s = __sinf(buf[T1_OFF + ml]);
        const f32x2 cc = {c, c}, ss = {s, s};
        const f32x2 a01 = {a4.x, a4.y}, a23 = {a4.z, a4.w};
        const f32x2 b01 = {b4.x, b4.y}, b23 = {b4.z, b4.w};
        f32x2 ure[2], uim[2];
        ure[0] = __builtin_elementwise_fma(-b01, ss, a01 * cc);  // a*c - b*s
        ure[1] = __builtin_elementwise_fma(-b23, ss, a23 * cc);
        uim[0] = __builtin_elementwise_fma( b01, cc, a01 * ss);  // a*s + b*c
        uim[1] = __builtin_elementwise_fma( b23, cc, a23 * ss);
        const float ev[4] = {e4.x, e4.y, e4.z, e4.w};
        const float fv[4] = {f4.x, f4.y, f4.z, f4.w};
#pragma unroll
        for (int i = 0; i < 4; ++i) {
            const f32x2 ee = {ev[i], ev[i]};
            const f32x2 ff = {fv[i], fv[i]};
#pragma unroll
            for (int jp = 0; jp < 2; ++jp) {
                are[i][jp] = __builtin_elementwise_fma( ee, ure[jp], are[i][jp]);
                are[i][jp] = __builtin_elementwise_fma(-ff, uim[jp], are[i][jp]);
                aim[i][jp] = __builtin_elementwise_fma( ee, uim[jp], aim[i][jp]);
                aim[i][jp] = __builtin_elementwise_fma( ff, ure[jp], aim[i][jp]);
            }
        }
    }
}

template <bool USE_ATOMIC>
__device__ __forceinline__ void theta_body(
    const float* __restrict__ gi, const float* __restrict__ gj,
    const float* __restrict__ theta, float* __restrict__ dst)
{
    __shared__ float smem[SMEM_F];               // 33792 B -> 4 blocks/CU
    const int t    = threadIdx.x;
    const int wave = t >> 6;
    const int lane = t & 63;
    const int slot = (lane >> 4) & 3;            // wave-local m slot (lane bits 4,5)
    const int tile = lane & 15;
    const int i0   = (tile >> 2) << 2;
    const int j0   = (tile & 3) << 2;
    const int m_w0 = blockIdx.x * M_PER_B + wave * M_PER_W;
    float* wbase   = smem + wave * WAVE_F;       // this wave's private region

    // Per-wave global base pointers (lane offset folded in).
    const float* e_g  = gi + (size_t)m_w0 * 16 + lane * 4;
    const float* f_g  = e_g + (size_t)MDIM * 16;
    const float* a_g  = gj + (size_t)m_w0 * 16 + lane * 4;
    const float* b_g  = a_g + (size_t)MDIM * 16;
    const float* t0_g = theta + m_w0 + lane;     // lanes < 16 only
    const float* t1_g = t0_g + MDIM;

    f32x2 are[4][2], aim[4][2];
#pragma unroll
    for (int i = 0; i < 4; ++i)
#pragma unroll
        for (int jp = 0; jp < 2; ++jp) { are[i][jp] = {0.f, 0.f}; aim[i][jp] = {0.f, 0.f}; }

    // Fill: chunks 0,1 in flight (12 loads). chunk c lives in buffer (c & 1).
    stage(e_g, f_g, a_g, b_g, t0_g, t1_g, wbase + 0 * BUF_F, 0, lane);
    stage(e_g, f_g, a_g, b_g, t0_g, t1_g, wbase + 1 * BUF_F, 1, lane);

    for (int c = 0; c < NCH - 2; ++c) {
        // Outstanding here: chunks c, c+1 (12 loads). Retire-in-order =>
        // <=6 means chunk c fully landed. No barrier: wave is sole
        // producer+consumer of its region.
        asm volatile("s_waitcnt vmcnt(6)" ::: "memory");
        compute_chunk(wbase + (c & 1) * BUF_F, slot, i0, j0, are, aim);
        // All ds_reads of chunk c must be SERVICED before the async
        // VMEM->LDS writes for chunk c+2 (same buffer) can land.
        asm volatile("s_waitcnt lgkmcnt(0)" ::: "memory");
        stage(e_g, f_g, a_g, b_g, t0_g, t1_g, wbase + (c & 1) * BUF_F, c + 2, lane);
    }
    asm volatile("s_waitcnt vmcnt(6)" ::: "memory");
    compute_chunk(wbase + ((NCH - 2) & 1) * BUF_F, slot, i0, j0, are, aim);
    asm volatile("s_waitcnt vmcnt(0)" ::: "memory");
    compute_chunk(wbase + ((NCH - 1) & 1) * BUF_F, slot, i0, j0, are, aim);

    // Unpack packed accumulators: j = jp*2 + half.
    float sre[4][4], sim[4][4];
#pragma unroll
    for (int i = 0; i < 4; ++i)
#pragma unroll
        for (int jp = 0; jp < 2; ++jp) {
            sre[i][jp * 2]     = are[i][jp].x;  sre[i][jp * 2 + 1] = are[i][jp].y;
            sim[i][jp * 2]     = aim[i][jp].x;  sim[i][jp * 2 + 1] = aim[i][jp].y;
        }

    // Fold the 4 m-slots (lane bits 4,5).
#pragma unroll
    for (int i = 0; i < 4; ++i)
#pragma unroll
        for (int j = 0; j < 4; ++j) {
            sre[i][j] += __shfl_xor(sre[i][j], 16);
            sre[i][j] += __shfl_xor(sre[i][j], 32);
            sim[i][j] += __shfl_xor(sim[i][j], 16);
            sim[i][j] += __shfl_xor(sim[i][j], 32);
        }

    // Fold the 4 waves via LDS (smem fully consumed; barrier makes reuse safe).
    __syncthreads();
    float (*red)[16][33] = (float (*)[16][33])smem;
    if (lane < 16) {
#pragma unroll
        for (int i = 0; i < 4; ++i)
#pragma unroll
            for (int j = 0; j < 4; ++j) {
                red[wave][lane][i * 4 + j]      = sre[i][j];
                red[wave][lane][16 + i * 4 + j] = sim[i][j];
            }
    }
    __syncthreads();

#pragma unroll
    for (int k = 0; k < 2; ++k) {
        const int idx = t * 2 + k;
        const int tl  = idx >> 5;
        const int v   = idx & 31;
        const float sum = red[0][tl][v] + red[1][tl][v] + red[2][tl][v] + red[3][tl][v];
        const int ii  = ((tl >> 2) << 2) + ((v & 15) >> 2);
        const int jj  = ((tl & 3) << 2) + (v & 3);
        const int off = ((v & 16) ? 256 : 0) + ii * 16 + jj;
        if (USE_ATOMIC) atomicAdd(dst + off, sum);
        else            dst[blockIdx.x * 512 + off] = sum;
    }
}

__global__ __launch_bounds__(THREADS) void theta_main_ws(
    const float* __restrict__ gi, const float* __restrict__ gj,
    const float* __restrict__ theta, float* __restrict__ partial)
{
    theta_body<false>(gi, gj, theta, partial);
}

__global__ __launch_bounds__(THREADS) void theta_main_atomic(
    const float* __restrict__ gi, const float* __restrict__ gj,
    const float* __restrict__ theta, float* __restrict__ out)
{
    theta_body<true>(gi, gj, theta, out);
}

// Stage 2: one wave per output element; fold BLOCKS partials + h bias.
__global__ __launch_bounds__(256) void theta_reduce(
    const float* __restrict__ h, const float* __restrict__ partial,
    float* __restrict__ out)
{
    const int w    = (blockIdx.x * 256 + threadIdx.x) >> 6;  // output index 0..511
    const int lane = threadIdx.x & 63;
    float s = 0.f;
#pragma unroll 4
    for (int j = 0; j < BLOCKS / 64; ++j)
        s += partial[(size_t)(j * 64 + lane) * 512 + w];
#pragma unroll
    for (int d = 1; d < 64; d <<= 1) s += __shfl_xor(s, d);
    if (lane == 0) out[w] = h[w] + s;
}

__global__ void theta_init(const float* __restrict__ h, float* __restrict__ out) {
    int k = blockIdx.x * blockDim.x + threadIdx.x;
    if (k < 512) out[k] = h[k];
}

extern "C" void kernel_launch(void* const* d_in, const int* in_sizes, int n_in,
                              void* d_out, int out_size, void* d_ws, size_t ws_size,
                              hipStream_t stream) {
    const float* h     = (const float*)d_in[0];
    const float* gi    = (const float*)d_in[1];
    const float* gj    = (const float*)d_in[2];
    const float* theta = (const float*)d_in[3];
    float* out = (float*)d_out;

    const size_t need = (size_t)BLOCKS * 512 * sizeof(float);  // 2 MB of partials
    if (ws_size >= need) {
        float* partial = (float*)d_ws;
        theta_main_ws<<<BLOCKS, THREADS, 0, stream>>>(gi, gj, theta, partial);
        theta_reduce<<<128, 256, 0, stream>>>(h, partial, out);
    } else {
        theta_init<<<2, 256, 0, stream>>>(h, out);
        theta_main_atomic<<<BLOCKS, THREADS, 0, stream>>>(gi, gj, theta, out);
    }
}

// Round 2
// 160.873 us; speedup vs baseline: 1.0266x; 1.0266x over previous
//
#include <hip/hip_runtime.h>

// h: (2,1,1,16,16) fp32 | gi: (2,M,16) | gj: (2,M,16) | theta: (2,M) | out: (2,16,16)
//
// History: R2 VGPR spill 199us. R3/R4 VGPR-loads 48us. R5 barrier dbuf 53us.
// R7 per-wave private LDS staging, DEPTH=3, 512 blocks (8 waves/CU): 51us.
// R8 DEPTH=2, 1024 blocks (16 waves/CU): 56.6us — REGRESSION. Key lesson:
// per-CU BW was 4.4 B/cyc (R7) vs 4.1 (R8) => wave-count-INDEPENDENT.
// Cap = per-CU miss-queue (~64 lines) x latency. Measured latency ~975 cyc
// == full HBM miss even with 50% L3 hits: per-wave private slabs mean the
// chip's outstanding set is ~4K scattered 1KB islands over 128 MB => DRAM
// row misses. The 6.3 TB/s copy ubench wins because grid-stride keeps a
// narrow DENSE window sweeping memory (row hits, ~400 cyc).
// R9 (this): R7 structure EXACTLY, but grid-strided chunk mapping:
// chunk c of global-wave gw reads m-chunk (c*GW + gw). For fixed c all 2048
// waves' 1KB requests are adjacent => dense sweeping front per array.
// Reduction is m-partition-agnostic; only the address map changes.

constexpr int MDIM    = 524288;
constexpr int THREADS = 256;
constexpr int BLOCKS  = 512;              // 2 blocks/CU (LDS-pinned)
constexpr int GW      = BLOCKS * 4;       // 2048 global waves
constexpr int CHUNK   = 16;               // m per chunk
constexpr int NCH     = MDIM / (GW * CHUNK);  // 16 chunks per wave
constexpr int DEPTH   = 3;                // buffers per wave (2 prefetched ahead)
static_assert(NCH * GW * CHUNK == MDIM, "exact tiling");

// Per-buffer float offsets: e[256] f[256] a[256] b[256] t0[16] t1[16]
constexpr int E_OFF = 0, F_OFF = 256, A_OFF = 512, B_OFF = 768;
constexpr int T0_OFF = 1024, T1_OFF = 1040;
constexpr int BUF_F  = 1056;
constexpr int WAVE_F = DEPTH * BUF_F;     // 3168 floats per wave
constexpr int SMEM_F = 4 * WAVE_F;        // 12672 floats = 50688 B
static_assert(SMEM_F * sizeof(float) <= 65536, "LDS must stay under 64 KiB");

// Chunk-to-chunk global stride (floats) for the e/f/a/b streams and theta.
constexpr size_t CSTRIDE_G = (size_t)GW * CHUNK * 16;  // 524288 floats = 2 MB
constexpr size_t CSTRIDE_T = (size_t)GW * CHUNK;       // 32768 floats

typedef float f32x2 __attribute__((ext_vector_type(2)));

#define AS1 __attribute__((address_space(1)))
#define AS3 __attribute__((address_space(3)))

__device__ __forceinline__ void cp16(const float* g, float* l) {
    __builtin_amdgcn_global_load_lds((const AS1 void*)g, (AS3 void*)l, 16, 0, 0);
}
__device__ __forceinline__ void cp4(const float* g, float* l) {
    __builtin_amdgcn_global_load_lds((const AS1 void*)g, (AS3 void*)l, 4, 0, 0);
}

// Stage chunk p into `buf`. Exactly 6 VMEM instructions per call for every
// wave (4 cp16 + 2 exec-masked cp4) — the vmcnt arithmetic depends on this.
__device__ __forceinline__ void stage(
    const float* e_g, const float* f_g, const float* a_g, const float* b_g,
    const float* t0_g, const float* t1_g, float* buf, int p, int lane)
{
    const size_t mo = (size_t)p * CSTRIDE_G;   // grid-strided chunk step
    cp16(e_g + mo, buf + E_OFF);
    cp16(f_g + mo, buf + F_OFF);
    cp16(a_g + mo, buf + A_OFF);
    cp16(b_g + mo, buf + B_OFF);
    if (lane < 16) {
        const size_t to = (size_t)p * CSTRIDE_T;
        cp4(t0_g + to, buf + T0_OFF);
        cp4(t1_g + to, buf + T1_OFF);
    }
}

__device__ __forceinline__ void compute_chunk(
    const float* buf, int slot, int i0, int j0,
    f32x2 (&are)[4][2], f32x2 (&aim)[4][2])
{
#pragma unroll
    for (int k = 0; k < 4; ++k) {
        const int ml = slot + 4 * k;             // 16 m per chunk, 4 per k-step
        const float4 e4 = *(const float4*)(buf + E_OFF + ml * 16 + i0);
        const float4 f4 = *(const float4*)(buf + F_OFF + ml * 16 + i0);
        const float4 a4 = *(const float4*)(buf + A_OFF + ml * 16 + j0);
        const float4 b4 = *(const float4*)(buf + B_OFF + ml * 16 + j0);
        const float c = __cosf(buf[T0_OFF + ml]);
        const float s = __sinf(buf[T1_OFF + ml]);
        const f32x2 cc = {c, c}, ss = {s, s};
        const f32x2 a01 = {a4.x, a4.y}, a23 = {a4.z, a4.w};
        const f32x2 b01 = {b4.x, b4.y}, b23 = {b4.z, b4.w};
        f32x2 ure[2], uim[2];
        ure[0] = __builtin_elementwise_fma(-b01, ss, a01 * cc);  // a*c - b*s
        ure[1] = __builtin_elementwise_fma(-b23, ss, a23 * cc);
        uim[0] = __builtin_elementwise_fma( b01, cc, a01 * ss);  // a*s + b*c
        uim[1] = __builtin_elementwise_fma( b23, cc, a23 * ss);
        const float ev[4] = {e4.x, e4.y, e4.z, e4.w};
        const float fv[4] = {f4.x, f4.y, f4.z, f4.w};
#pragma unroll
        for (int i = 0; i < 4; ++i) {
            const f32x2 ee = {ev[i], ev[i]};
            const f32x2 ff = {fv[i], fv[i]};
#pragma unroll
            for (int jp = 0; jp < 2; ++jp) {
                are[i][jp] = __builtin_elementwise_fma( ee, ure[jp], are[i][jp]);
                are[i][jp] = __builtin_elementwise_fma(-ff, uim[jp], are[i][jp]);
                aim[i][jp] = __builtin_elementwise_fma( ee, uim[jp], aim[i][jp]);
                aim[i][jp] = __builtin_elementwise_fma( ff, ure[jp], aim[i][jp]);
            }
        }
    }
}

template <bool USE_ATOMIC>
__device__ __forceinline__ void theta_body(
    const float* __restrict__ gi, const float* __restrict__ gj,
    const float* __restrict__ theta, float* __restrict__ dst)
{
    __shared__ float smem[SMEM_F];               // 50688 B -> 2 blocks/CU
    const int t    = threadIdx.x;
    const int wave = t >> 6;
    const int lane = t & 63;
    const int slot = (lane >> 4) & 3;            // wave-local m slot (lane bits 4,5)
    const int tile = lane & 15;
    const int i0   = (tile >> 2) << 2;
    const int j0   = (tile & 3) << 2;
    const int gw   = blockIdx.x * 4 + wave;      // global wave id 0..GW-1
    float* wbase   = smem + wave * WAVE_F;       // this wave's private region

    // Per-wave global base pointers: wave gw owns m-chunks {c*GW + gw}.
    const float* e_g  = gi + (size_t)gw * (CHUNK * 16) + lane * 4;
    const float* f_g  = e_g + (size_t)MDIM * 16;
    const float* a_g  = gj + (size_t)gw * (CHUNK * 16) + lane * 4;
    const float* b_g  = a_g + (size_t)MDIM * 16;
    const float* t0_g = theta + (size_t)gw * CHUNK + lane;  // lanes < 16 only
    const float* t1_g = t0_g + MDIM;

    f32x2 are[4][2], aim[4][2];
#pragma unroll
    for (int i = 0; i < 4; ++i)
#pragma unroll
        for (int jp = 0; jp < 2; ++jp) { are[i][jp] = {0.f, 0.f}; aim[i][jp] = {0.f, 0.f}; }

    // Fill: chunks 0,1 in flight (12 loads).
    stage(e_g, f_g, a_g, b_g, t0_g, t1_g, wbase + 0 * BUF_F, 0, lane);
    stage(e_g, f_g, a_g, b_g, t0_g, t1_g, wbase + 1 * BUF_F, 1, lane);

    int sb = 2, cb = 0;
    for (int c = 0; c < NCH - 2; ++c) {
        stage(e_g, f_g, a_g, b_g, t0_g, t1_g, wbase + sb * BUF_F, c + 2, lane);
        sb = (sb == DEPTH - 1) ? 0 : sb + 1;
        // 18 outstanding (chunks c,c+1,c+2); retire-in-order => <=12 means
        // chunk c fully landed. No barrier: this wave is sole producer+consumer.
        asm volatile("s_waitcnt vmcnt(12)" ::: "memory");
        compute_chunk(wbase + cb * BUF_F, slot, i0, j0, are, aim);
        cb = (cb == DEPTH - 1) ? 0 : cb + 1;
    }
    asm volatile("s_waitcnt vmcnt(6)" ::: "memory");
    compute_chunk(wbase + cb * BUF_F, slot, i0, j0, are, aim);
    cb = (cb == DEPTH - 1) ? 0 : cb + 1;
    asm volatile("s_waitcnt vmcnt(0)" ::: "memory");
    compute_chunk(wbase + cb * BUF_F, slot, i0, j0, are, aim);

    // Unpack packed accumulators: j = jp*2 + half.
    float sre[4][4], sim[4][4];
#pragma unroll
    for (int i = 0; i < 4; ++i)
#pragma unroll
        for (int jp = 0; jp < 2; ++jp) {
            sre[i][jp * 2]     = are[i][jp].x;  sre[i][jp * 2 + 1] = are[i][jp].y;
            sim[i][jp * 2]     = aim[i][jp].x;  sim[i][jp * 2 + 1] = aim[i][jp].y;
        }

    // Fold the 4 m-slots (lane bits 4,5).
#pragma unroll
    for (int i = 0; i < 4; ++i)
#pragma unroll
        for (int j = 0; j < 4; ++j) {
            sre[i][j] += __shfl_xor(sre[i][j], 16);
            sre[i][j] += __shfl_xor(sre[i][j], 32);
            sim[i][j] += __shfl_xor(sim[i][j], 16);
            sim[i][j] += __shfl_xor(sim[i][j], 32);
        }

    // Fold the 4 waves via LDS (smem fully consumed; barrier makes reuse safe).
    __syncthreads();
    float (*red)[16][33] = (float (*)[16][33])smem;
    if (lane < 16) {
#pragma unroll
        for (int i = 0; i < 4; ++i)
#pragma unroll
            for (int j = 0; j < 4; ++j) {
                red[wave][lane][i * 4 + j]      = sre[i][j];
                red[wave][lane][16 + i * 4 + j] = sim[i][j];
            }
    }
    __syncthreads();

#pragma unroll
    for (int k = 0; k < 2; ++k) {
        const int idx = t * 2 + k;
        const int tl  = idx >> 5;
        const int v   = idx & 31;
        const float sum = red[0][tl][v] + red[1][tl][v] + red[2][tl][v] + red[3][tl][v];
        const int ii  = ((tl >> 2) << 2) + ((v & 15) >> 2);
        const int jj  = ((tl & 3) << 2) + (v & 3);
        const int off = ((v & 16) ? 256 : 0) + ii * 16 + jj;
        if (USE_ATOMIC) atomicAdd(dst + off, sum);
        else            dst[blockIdx.x * 512 + off] = sum;
    }
}

__global__ __launch_bounds__(THREADS) void theta_main_ws(
    const float* __restrict__ gi, const float* __restrict__ gj,
    const float* __restrict__ theta, float* __restrict__ partial)
{
    theta_body<false>(gi, gj, theta, partial);
}

__global__ __launch_bounds__(THREADS) void theta_main_atomic(
    const float* __restrict__ gi, const float* __restrict__ gj,
    const float* __restrict__ theta, float* __restrict__ out)
{
    theta_body<true>(gi, gj, theta, out);
}

// Stage 2: one wave per output element; fold BLOCKS partials + h bias.
__global__ __launch_bounds__(256) void theta_reduce(
    const float* __restrict__ h, const float* __restrict__ partial,
    float* __restrict__ out)
{
    const int w    = (blockIdx.x * 256 + threadIdx.x) >> 6;  // output index 0..511
    const int lane = threadIdx.x & 63;
    float s = 0.f;
#pragma unroll 4
    for (int j = 0; j < BLOCKS / 64; ++j)
        s += partial[(size_t)(j * 64 + lane) * 512 + w];
#pragma unroll
    for (int d = 1; d < 64; d <<= 1) s += __shfl_xor(s, d);
    if (lane == 0) out[w] = h[w] + s;
}

__global__ void theta_init(const float* __restrict__ h, float* __restrict__ out) {
    int k = blockIdx.x * blockDim.x + threadIdx.x;
    if (k < 512) out[k] = h[k];
}

extern "C" void kernel_launch(void* const* d_in, const int* in_sizes, int n_in,
                              void* d_out, int out_size, void* d_ws, size_t ws_size,
                              hipStream_t stream) {
    const float* h     = (const float*)d_in[0];
    const float* gi    = (const float*)d_in[1];
    const float* gj    = (const float*)d_in[2];
    const float* theta = (const float*)d_in[3];
    float* out = (float*)d_out;

    const size_t need = (size_t)BLOCKS * 512 * sizeof(float);  // 1 MB of partials
    if (ws_size >= need) {
        float* partial = (float*)d_ws;
        theta_main_ws<<<BLOCKS, THREADS, 0, stream>>>(gi, gj, theta, partial);
        theta_reduce<<<128, 256, 0, stream>>>(h, partial, out);
    } else {
        theta_init<<<2, 256, 0, stream>>>(h, out);
        theta_main_atomic<<<BLOCKS, THREADS, 0, stream>>>(gi, gj, theta, out);
    }
}